// Round 1
// 119.511 us; speedup vs baseline: 1.0005x; 1.0005x over previous
//
#include <hip/hip_runtime.h>
#include <math.h>

#define BB 512
#define LL 128
#define DD 256
#define NREST 127            // L-1
#define EPSN 1e-12f

#define TI 128               // i-tile and k-tile per block

typedef float f32x4 __attribute__((ext_vector_type(4)));
typedef int   i32x4 __attribute__((ext_vector_type(4)));
typedef int   i32x8 __attribute__((ext_vector_type(8)));

// async global->LDS, 16B per lane; LDS base wave-uniform (HW adds lane*16)
#define GLD16(gp, lp) __builtin_amdgcn_global_load_lds( \
    (const __attribute__((address_space(1))) void*)(gp), \
    (__attribute__((address_space(3))) void*)(lp), 16, 0, 0)

// ---- Kernel 1: norm + normalize + cvt fp8(e4m3), piece-swizzled rows ----
// Row layout (256 B): 16 pieces of 16 B; piece p of row r stored at slot
// p ^ (r & 15). This makes the 16x16x128 MFMA fragment reads (lane = row
// lane&15, k-chunk = quad*32, two ds_read_b128) bank-conflict-free: slot
// low-3-bits spread 64 lanes evenly over all 8 four-bank groups.
// Rf[b][r] holds row l=r+1; Rf[b][127] zeroed (pad). Block 0 zeroes tot/pos.
__global__ __launch_bounds__(256) void prep_kernel(const float* __restrict__ in,
                                                   unsigned char* __restrict__ Af,
                                                   unsigned char* __restrict__ Rf,
                                                   float* __restrict__ totpos) {
    if (blockIdx.x == 0) {
        ((f32x4*)totpos)[threadIdx.x] = (f32x4){0.f, 0.f, 0.f, 0.f};  // 1024 floats
    }
    int wid  = threadIdx.x >> 6;
    int lane = threadIdx.x & 63;
    int row  = blockIdx.x * 4 + wid;            // 0..65535
    int b    = row >> 7;
    int l    = row & 127;
    const float4 v = ((const float4*)(in + (size_t)row * DD))[lane];
    float ss = v.x*v.x + v.y*v.y + v.z*v.z + v.w*v.w;
    #pragma unroll
    for (int off = 32; off; off >>= 1) ss += __shfl_xor(ss, off);
    float sc = 1.0f / fmaxf(sqrtf(ss), EPSN);

    int p = __builtin_amdgcn_cvt_pk_fp8_f32(v.x * sc, v.y * sc, 0, false);
    p     = __builtin_amdgcn_cvt_pk_fp8_f32(v.z * sc, v.w * sc, p, true);

    // lane handles original bytes 4*lane..4*lane+3 of its row
    int piece = lane >> 2;            // 16B piece 0..15
    int sub   = (lane & 3) << 2;      // dword within piece

    if (l == 0) {
        int off = ((piece ^ (b & 15)) << 4) + sub;
        *(unsigned int*)(Af + (size_t)b * DD + off) = (unsigned int)p;
        int offp = ((piece ^ 15) << 4) + sub;      // pad row key = 127&15
        *(unsigned int*)(Rf + ((size_t)b * LL + 127) * DD + offp) = 0u;
    } else {
        int r   = l - 1;
        int off = ((piece ^ (r & 15)) << 4) + sub;
        *(unsigned int*)(Rf + ((size_t)b * LL + r) * DD + off) = (unsigned int)p;
    }
}

// ------- Kernel 2: MX-scaled fp8 MFMA (K=128, unit scales) + exp + k-sum -------
// Block: 128 anchors x 128 rest rows of batch j. Full K=256 staged upfront
// (64 KB LDS, pure linear 1KB-chunk copy since swizzle is baked into the
// global layout), ONE barrier, 32 MFMA/wave (16x16x128 f8f6f4, fp8 e4m3,
// scale = 0x7F -> x1.0), then exp + per-i sums + device atomicAdd.
__global__ __launch_bounds__(256) void score_kernel(const unsigned char* __restrict__ Af,
                                                    const unsigned char* __restrict__ Rf,
                                                    const int* __restrict__ label,
                                                    float* __restrict__ tot,
                                                    float* __restrict__ pos) {
    __shared__ unsigned char sA[TI * DD];   // 32 KB (swizzled rows, linear copy)
    __shared__ unsigned char sR[TI * DD];   // 32 KB
    __shared__ float         sP[TI * 2];

    const int tid  = threadIdx.x;
    const int i0   = blockIdx.x * TI;
    const int j    = blockIdx.y;

    const int lane = tid & 63;
    const int w    = tid >> 6;
    const int wm   = w & 1;            // wave row (i half)
    const int wn   = w >> 1;           // wave col (k_rest half)
    const int rowf = lane & 15;
    const int quad = lane >> 4;

    const unsigned char* aBase = Af + (size_t)i0 * DD;
    const unsigned char* rBase = Rf + (size_t)j * LL * DD;

    // ---- stage ALL of K: 64 x 1KB linear async copies, one barrier ----
    #pragma unroll
    for (int t = 0; t < 8; ++t) {
        int c = w * 8 + t;             // 1KB chunk 0..31 (4 rows each)
        GLD16(aBase + (size_t)c * 1024 + lane * 16, &sA[c * 1024]);
        GLD16(rBase + (size_t)c * 1024 + lane * 16, &sR[c * 1024]);
    }

    f32x4 acc[4][4];
    #pragma unroll
    for (int a = 0; a < 4; ++a)
        #pragma unroll
        for (int b = 0; b < 4; ++b) acc[a][b] = (f32x4){0.f, 0.f, 0.f, 0.f};

    __syncthreads();

    // ---- 2 K-steps of 128, 16 MFMA each; fragment reads conflict-free ----
    // A/B frag (16x16x128 f8f6f4): row/col = lane&15, k = quad*32 + byte.
    // Piece indices ks*8 + quad*2 {+1}; stored at slot (piece ^ rowf).
    #pragma unroll
    for (int ks = 0; ks < 2; ++ks) {
        const int o0 = (((ks * 8 + quad * 2) ^ rowf) << 4);
        const int o1 = o0 ^ 16;        // slot of piece+1 (base piece is even)
        i32x8 af[4], bf[4];
        #pragma unroll
        for (int mt = 0; mt < 4; ++mt) {
            const unsigned char* rp = &sA[(wm * 64 + mt * 16 + rowf) * DD];
            i32x4 lo = *(const i32x4*)(rp + o0);
            i32x4 hi = *(const i32x4*)(rp + o1);
            af[mt] = __builtin_shufflevector(lo, hi, 0, 1, 2, 3, 4, 5, 6, 7);
        }
        #pragma unroll
        for (int nt = 0; nt < 4; ++nt) {
            const unsigned char* rp = &sR[(wn * 64 + nt * 16 + rowf) * DD];
            i32x4 lo = *(const i32x4*)(rp + o0);
            i32x4 hi = *(const i32x4*)(rp + o1);
            bf[nt] = __builtin_shufflevector(lo, hi, 0, 1, 2, 3, 4, 5, 6, 7);
        }
        #pragma unroll
        for (int mt = 0; mt < 4; ++mt)
            #pragma unroll
            for (int nt = 0; nt < 4; ++nt)
                acc[mt][nt] = __builtin_amdgcn_mfma_scale_f32_16x16x128_f8f6f4(
                    af[mt], bf[nt], acc[mt][nt],
                    0, 0,                 // cbsz=fp8(e4m3), blgp=fp8(e4m3)
                    0, 0x7f7f7f7f,        // scale A: e8m0 127 -> x1.0
                    0, 0x7f7f7f7f);       // scale B: x1.0
    }

    // ---- epilogue: exp + sum over this wave's 64 k values ----
    // C/D layout: col(n) = lane&15, row(m) = quad*4 + reg (shape-determined,
    // identical to the previously verified 16x16x32 path)
    #pragma unroll
    for (int mt = 0; mt < 4; ++mt) {
        float s[4];
        #pragma unroll
        for (int r = 0; r < 4; ++r) s[r] = 0.f;
        #pragma unroll
        for (int nt = 0; nt < 4; ++nt) {
            int n = wn * 64 + nt * 16 + rowf;   // global k_rest index
            bool valid = (n < NREST);
            #pragma unroll
            for (int r = 0; r < 4; ++r)
                if (valid) s[r] += __expf(acc[mt][nt][r]);
        }
        #pragma unroll
        for (int r = 0; r < 4; ++r) {
            #pragma unroll
            for (int off = 1; off < 16; off <<= 1) s[r] += __shfl_xor(s[r], off);
        }
        if (rowf == 0) {
            #pragma unroll
            for (int r = 0; r < 4; ++r)
                sP[(wm * 64 + mt * 16 + quad * 4 + r) * 2 + wn] = s[r];
        }
    }
    __syncthreads();
    if (tid < TI) {
        int i = i0 + tid;
        float e = sP[tid * 2] + sP[tid * 2 + 1];
        atomicAdd(&tot[i], e);
        if (label[j] == label[i]) atomicAdd(&pos[i], e);
    }
}

// ---- Kernel 3: loss = mean_i( log tot[i] - log pos[i] ) ----
__global__ __launch_bounds__(256) void final_kernel(const float* __restrict__ tot,
                                                    const float* __restrict__ pos,
                                                    float* __restrict__ out) {
    int t0 = threadIdx.x, t1 = threadIdx.x + 256;
    float s = (logf(tot[t0]) - logf(pos[t0])) + (logf(tot[t1]) - logf(pos[t1]));
    #pragma unroll
    for (int off = 32; off; off >>= 1) s += __shfl_xor(s, off);
    __shared__ float sw[4];
    int wid = threadIdx.x >> 6;
    if ((threadIdx.x & 63) == 0) sw[wid] = s;
    __syncthreads();
    if (threadIdx.x == 0) out[0] = (sw[0] + sw[1] + sw[2] + sw[3]) * (1.0f / BB);
}

extern "C" void kernel_launch(void* const* d_in, const int* in_sizes, int n_in,
                              void* d_out, int out_size, void* d_ws, size_t ws_size,
                              hipStream_t stream) {
    const float* in    = (const float*)d_in[0];
    const int*   label = (const int*)d_in[1];
    float*       out   = (float*)d_out;

    unsigned char* Af  = (unsigned char*)d_ws;               // 512*256 B (128 KB)
    unsigned char* Rf  = Af + (size_t)BB * DD;               // 512*128*256 B (16 MB)
    float*         tot = (float*)(Rf + (size_t)BB * LL * DD); // 512 f32
    float*         pos = tot + BB;                            // 512 f32

    prep_kernel<<<(BB * LL) / 4, 256, 0, stream>>>(in, Af, Rf, tot);
    score_kernel<<<dim3(BB / TI, BB), 256, 0, stream>>>(Af, Rf, label, tot, pos);
    final_kernel<<<1, 256, 0, stream>>>(tot, pos, out);
}